// Round 20
// baseline (275.991 us; speedup 1.0000x reference)
//
#include <hip/hip_runtime.h>

#define NFEAT 128
#define RS 128   // bf16 plane row stride in shorts

using bf16x8 = __attribute__((ext_vector_type(8))) short;
using f32x4  = __attribute__((ext_vector_type(4))) float;
using f32x2  = __attribute__((ext_vector_type(2))) float;

__device__ __forceinline__ float bf2f(unsigned short u) {
    union { unsigned int i; float f; } v; v.i = ((unsigned int)u) << 16; return v.f;
}
__device__ __forceinline__ unsigned short f2bf(float f) {      // RNE
    union { float f; unsigned int i; } v; v.f = f;
    unsigned int i = v.i;
    return (unsigned short)((i + 0x7FFFu + ((i >> 16) & 1u)) >> 16);
}
__device__ __forceinline__ unsigned int f4_to_fp8x4(float f0, float f1, float f2, float f3) {
    int p = __builtin_amdgcn_cvt_pk_fp8_f32(f0, f1, 0, false);
    p     = __builtin_amdgcn_cvt_pk_fp8_f32(f2, f3, p, true);
    return (unsigned int)p;
}

// ---------------- CSR build (XCD-sliced hist/fill) ----------------

__global__ void hist_kernel(const int* __restrict__ dst, int* __restrict__ cnt,
                            int nE, int sliceN) {
    const int slice = blockIdx.x & 7;
    const int lo = slice * sliceN, hi = lo + sliceN;
    const int nb = gridDim.x >> 3;
    const int bs = blockIdx.x >> 3;
    for (int i = bs * 256 + threadIdx.x; i < nE; i += nb * 256) {
        int d = dst[i];
        if (d >= lo && d < hi) atomicAdd(&cnt[d], 1);
    }
}

__global__ void fill_kernel(const int* __restrict__ src, const int* __restrict__ dst,
                            int* __restrict__ cnt, int* __restrict__ col_idx,
                            int nE, int sliceN) {
    const int slice = blockIdx.x & 7;
    const int lo = slice * sliceN, hi = lo + sliceN;
    const int nb = gridDim.x >> 3;
    const int bs = blockIdx.x >> 3;
    for (int i = bs * 256 + threadIdx.x; i < nE; i += nb * 256) {
        int d = dst[i];
        int s = src[i];
        if (d >= lo && d < hi) {
            int pos = atomicAdd(&cnt[d], 1);
            col_idx[pos] = s;
        }
    }
}

__global__ void blocksum_kernel(const int* __restrict__ cnt, int* __restrict__ blockSum, int n) {
    int i = blockIdx.x * 256 + threadIdx.x;
    int d = (i < n) ? cnt[i] : 0;
    int lane = threadIdx.x & 63, wid = threadIdx.x >> 6;
    __shared__ int ws[4];
    int v = d;
    for (int off = 32; off; off >>= 1) v += __shfl_down(v, off);
    if (lane == 0) ws[wid] = v;
    __syncthreads();
    if (threadIdx.x == 0) blockSum[blockIdx.x] = ws[0] + ws[1] + ws[2] + ws[3];
}

// degree histogram via per-block LDS aggregation (round-16 lesson)
__global__ void scan_write_kernel(int* __restrict__ cnt, const int* __restrict__ blockSum,
                                  int* __restrict__ row_ptr, float* __restrict__ inv_deg,
                                  int* __restrict__ degHist, int n) {
    const int b = blockIdx.x, tid = threadIdx.x;
    const int lane = tid & 63, wid = tid >> 6;
    __shared__ int wsA[4];
    __shared__ int wsB[4];
    __shared__ int lhist[256];
    lhist[tid] = 0;
    int v = (tid < b) ? blockSum[tid] : 0;
    for (int off = 32; off; off >>= 1) v += __shfl_down(v, off);
    if (lane == 0) wsA[wid] = v;
    int i = b * 256 + tid;
    int d = (i < n) ? cnt[i] : 0;
    int s = d;
    for (int off = 1; off < 64; off <<= 1) {
        int t = __shfl_up(s, off);
        if (lane >= off) s += t;
    }
    if (lane == 63) wsB[wid] = s;
    __syncthreads();
    int blockOff = wsA[0] + wsA[1] + wsA[2] + wsA[3];
    int wOff = 0;
    for (int w = 0; w < wid; ++w) wOff += wsB[w];
    int excl = blockOff + wOff + s - d;
    if (i < n) {
        row_ptr[i] = excl;
        cnt[i]     = excl;
        inv_deg[i] = 1.0f / (float)(d > 1 ? d : 1);
        atomicAdd(&lhist[d > 255 ? 255 : d], 1);
    }
    if (i == n) row_ptr[n] = excl;
    __syncthreads();
    if (lhist[tid] > 0) atomicAdd(&degHist[tid], lhist[tid]);
}

// DESCENDING-degree bin cursors: heavy nodes first (LPT scheduling, round-19 win)
__global__ void bin_scan_kernel(int* __restrict__ dh) {
    const int tid = threadIdx.x, lane = tid & 63, w = tid >> 6;
    __shared__ int ws[4];
    const int idx = 255 - tid;          // process bins in reverse
    int v = dh[idx];
    int s = v;
    for (int off = 1; off < 64; off <<= 1) {
        int t = __shfl_up(s, off);
        if (lane >= off) s += t;
    }
    if (lane == 63) ws[w] = s;
    __syncthreads();
    int woff = 0;
    for (int i = 0; i < w; ++i) woff += ws[i];
    dh[idx] = woff + s - v;             // = count of nodes with degree > idx
}

// degree-sorted permutation, LDS-aggregated
__global__ void scatter_kernel(const int* __restrict__ row_ptr, int* __restrict__ cursor,
                               int* __restrict__ perm, int n) {
    __shared__ int lhist[256];
    __shared__ int lbase[256];
    const int tid = threadIdx.x;
    lhist[tid] = 0;
    __syncthreads();
    int i = blockIdx.x * 256 + tid;
    int d = 0, lr = 0;
    if (i < n) {
        d = row_ptr[i + 1] - row_ptr[i];
        if (d > 255) d = 255;
        lr = atomicAdd(&lhist[d], 1);
    }
    __syncthreads();
    if (lhist[tid] > 0) lbase[tid] = atomicAdd(&cursor[tid], lhist[tid]);
    __syncthreads();
    if (i < n) perm[lbase[d] + lr] = i;
}

// ---------------- fused prep: xconv + all wconv + zero(cnt,degHist) ----------------

__global__ void prep_kernel(const float* __restrict__ x,
                            unsigned short* __restrict__ xc, unsigned char* __restrict__ xq,
                            const float* __restrict__ Wl0, const float* __restrict__ Wr0,
                            const float* __restrict__ Wl1, const float* __restrict__ Wr1,
                            const float* __restrict__ Wl2, const float* __restrict__ Wr2,
                            unsigned short* __restrict__ Wsz0,
                            unsigned short* __restrict__ Wsz1,
                            unsigned short* __restrict__ Wsz2,
                            int* __restrict__ cnt, int* __restrict__ degHist, int n) {
    int idx = blockIdx.x * 256 + threadIdx.x;
    const int R0 = n * 32;
    if (idx < R0) {
        int node = idx >> 5, fb = (idx & 31) * 4;
        float4 v = *(const float4*)(x + (size_t)node * NFEAT + fb);
        uint2 hw;
        hw.x = (unsigned int)f2bf(v.x) | ((unsigned int)f2bf(v.y) << 16);
        hw.y = (unsigned int)f2bf(v.z) | ((unsigned int)f2bf(v.w) << 16);
        *(uint2*)(xc + (size_t)node * RS + fb) = hw;
        *(unsigned int*)(xq + (size_t)node * NFEAT + fb) = f4_to_fp8x4(v.x, v.y, v.z, v.w);
        return;
    }
    idx -= R0;
    if (idx < 81920) {
        const float* Wl; const float* Wr; unsigned short* Wsz; int nout; int li;
        if (idx < 32768)      { Wl = Wl0; Wr = Wr0; Wsz = Wsz0; nout = 128; li = idx; }
        else if (idx < 65536) { Wl = Wl1; Wr = Wr1; Wsz = Wsz1; nout = 128; li = idx - 32768; }
        else                  { Wl = Wl2; Wr = Wr2; Wsz = Wsz2; nout = 64;  li = idx - 65536; }
        int c = li >> 8, k = li & 255;
        float f = (k < 128) ? Wl[k * nout + c] : Wr[(k - 128) * nout + c];
        Wsz[c * 256 + (k ^ ((c & 7) << 3))] = f2bf(f);
        return;
    }
    idx -= 81920;
    if (idx < n) { cnt[idx] = 0; return; }
    idx -= n;
    if (idx < 256) degHist[idx] = 0;
}

// ---------------- fused layer: gather-mean (fp8) -> LDS -> MFMA GEMM ----------------
// Round-20: the gather's 8-edge load batch is forced with INLINE ASM -- one asm
// block issues 8 global_load_dwordx4 back-to-back (forced-live dests), then
// s_waitcnt vmcnt(0) + sched_barrier(0) (rule-18 fence), then consume. Rounds
// 17/18 showed launch_bounds cannot stop the scheduler from serializing the
// batch (it targets the LDS-implied 6 waves/SIMD ~ 85 VGPR and sinks loads);
// asm is scheduler-proof. Accumulator shrunk to one a[16] (reorder-only FP
// change) to keep peak live ~110 < the (512,4) cap of 128 -> no spill.

template<int NOUT, bool RELU, bool FINAL>
__global__ __launch_bounds__(512, 4) void layer_kernel(
    const unsigned char* __restrict__ xq, const unsigned short* __restrict__ xc,
    const int* __restrict__ row_ptr, const int* __restrict__ col_idx,
    const float* __restrict__ inv_deg, const int* __restrict__ perm,
    const unsigned short* __restrict__ Wsz, const float* __restrict__ bias,
    float* __restrict__ outF, unsigned short* __restrict__ outC,
    unsigned char* __restrict__ outQ, int n)
{
    constexpr int HALVES = NOUT / 64;
    constexpr int AOFF = 32768;
    __shared__ char smem[32768 + 16384];   // W half (32KB) | A tile (16KB)
    const int tid  = threadIdx.x;
    const int lane = tid & 63;
    const int wid  = tid >> 6;             // 0..7
    const int rowBase = blockIdx.x * 64;

    // ---- stage W half 0 via global_load_lds (lane-linear) ----
    {
        const char* wsrc = (const char*)Wsz;
        #pragma unroll
        for (int i = 0; i < 4; ++i) {
            const int off = (i * 512 + tid) * 16;
            __builtin_amdgcn_global_load_lds(
                (const __attribute__((address_space(1))) unsigned int*)(wsrc + off),
                (__attribute__((address_space(3))) unsigned int*)(smem + off),
                16, 0, 0);
        }
    }

    // ---- x-side prefetch (ks 4..7) for this thread's GEMM rows ----
    const int lrow = lane & 15;
    const int lk   = (lane >> 4) * 8;
    const int rg   = wid >> 1;             // row group (16 rows each)
    const int cg   = wid & 1;              // col group (32 cols each)
    int ri0 = rowBase + rg * 16 + lrow; if (ri0 > n - 1) ri0 = n - 1;
    const int xnode = perm[ri0];
    const unsigned short* Xr = xc + (size_t)xnode * RS;
    bf16x8 xr[4];
    #pragma unroll
    for (int ks = 0; ks < 4; ++ks) xr[ks] = *(const bf16x8*)(Xr + ks * 32 + lk);
    __builtin_amdgcn_sched_barrier(0);

    // ---- gather: 64 nodes (degree-sorted), 8 lanes/node, fp8 rows ----
    {
        const int l    = tid & 7;
        const int nd   = tid >> 3;         // 0..63 block-local
        int pidx = rowBase + nd; if (pidx > n - 1) pidx = n - 1;
        const int node = perm[pidx];
        int beg = row_ptr[node], end = row_ptr[node + 1];
        float a[16];
        #pragma unroll
        for (int j = 0; j < 16; ++j) a[j] = 0.f;
        auto acc16 = [&](float* A, uint4 v) {
            f32x2 d;
            d = __builtin_amdgcn_cvt_pk_f32_fp8(v.x, false); A[0]  += d[0]; A[1]  += d[1];
            d = __builtin_amdgcn_cvt_pk_f32_fp8(v.x, true);  A[2]  += d[0]; A[3]  += d[1];
            d = __builtin_amdgcn_cvt_pk_f32_fp8(v.y, false); A[4]  += d[0]; A[5]  += d[1];
            d = __builtin_amdgcn_cvt_pk_f32_fp8(v.y, true);  A[6]  += d[0]; A[7]  += d[1];
            d = __builtin_amdgcn_cvt_pk_f32_fp8(v.z, false); A[8]  += d[0]; A[9]  += d[1];
            d = __builtin_amdgcn_cvt_pk_f32_fp8(v.z, true);  A[10] += d[0]; A[11] += d[1];
            d = __builtin_amdgcn_cvt_pk_f32_fp8(v.w, false); A[12] += d[0]; A[13] += d[1];
            d = __builtin_amdgcn_cvt_pk_f32_fp8(v.w, true);  A[14] += d[0]; A[15] += d[1];
        };
        const unsigned char* xqb = xq + l * 16;
        int e = beg;
        for (; e + 8 <= end; e += 8) {
            const unsigned char* p0 = xqb + (size_t)col_idx[e + 0] * NFEAT;
            const unsigned char* p1 = xqb + (size_t)col_idx[e + 1] * NFEAT;
            const unsigned char* p2 = xqb + (size_t)col_idx[e + 2] * NFEAT;
            const unsigned char* p3 = xqb + (size_t)col_idx[e + 3] * NFEAT;
            const unsigned char* p4 = xqb + (size_t)col_idx[e + 4] * NFEAT;
            const unsigned char* p5 = xqb + (size_t)col_idx[e + 5] * NFEAT;
            const unsigned char* p6 = xqb + (size_t)col_idx[e + 6] * NFEAT;
            const unsigned char* p7 = xqb + (size_t)col_idx[e + 7] * NFEAT;
            uint4 v0, v1, v2, v3, v4, v5, v6, v7;
            asm volatile(
                "global_load_dwordx4 %0, %8, off\n\t"
                "global_load_dwordx4 %1, %9, off\n\t"
                "global_load_dwordx4 %2, %10, off\n\t"
                "global_load_dwordx4 %3, %11, off\n\t"
                "global_load_dwordx4 %4, %12, off\n\t"
                "global_load_dwordx4 %5, %13, off\n\t"
                "global_load_dwordx4 %6, %14, off\n\t"
                "global_load_dwordx4 %7, %15, off"
                : "=&v"(v0), "=&v"(v1), "=&v"(v2), "=&v"(v3),
                  "=&v"(v4), "=&v"(v5), "=&v"(v6), "=&v"(v7)
                : "v"(p0), "v"(p1), "v"(p2), "v"(p3),
                  "v"(p4), "v"(p5), "v"(p6), "v"(p7));
            asm volatile("s_waitcnt vmcnt(0)" ::: "memory");
            __builtin_amdgcn_sched_barrier(0);
            acc16(a, v0); acc16(a, v1); acc16(a, v2); acc16(a, v3);
            acc16(a, v4); acc16(a, v5); acc16(a, v6); acc16(a, v7);
        }
        for (; e < end; ++e) {
            int s = col_idx[e];
            uint4 v = *(const uint4*)(xqb + (size_t)s * NFEAT);
            acc16(a, v);
        }
        float sc = inv_deg[node];
        unsigned short hs[16];
        #pragma unroll
        for (int j = 0; j < 16; ++j)
            hs[j] = f2bf(a[j] * sc);
        uint4 h0, h1;
        h0.x = (unsigned int)hs[0]  | ((unsigned int)hs[1]  << 16);
        h0.y = (unsigned int)hs[2]  | ((unsigned int)hs[3]  << 16);
        h0.z = (unsigned int)hs[4]  | ((unsigned int)hs[5]  << 16);
        h0.w = (unsigned int)hs[6]  | ((unsigned int)hs[7]  << 16);
        h1.x = (unsigned int)hs[8]  | ((unsigned int)hs[9]  << 16);
        h1.y = (unsigned int)hs[10] | ((unsigned int)hs[11] << 16);
        h1.z = (unsigned int)hs[12] | ((unsigned int)hs[13] << 16);
        h1.w = (unsigned int)hs[14] | ((unsigned int)hs[15] << 16);
        const int s_ = nd & 7;
        char* arow = smem + AOFF + nd * 256;
        *(uint4*)(arow + (((2 * l)     ^ s_) << 4)) = h0;
        *(uint4*)(arow + (((2 * l + 1) ^ s_) << 4)) = h1;
    }

    __syncthreads();                       // W half0 + A tile + xr all resident

    const int cc0 = cg * 32 + lrow;
    const int cc1 = cg * 32 + 16 + lrow;
    const int cb0 = (cc0 << 9) + ((lane >> 4) * 16), xm0 = (cc0 & 7) << 4;
    const int cb1 = (cc1 << 9) + ((lane >> 4) * 16), xm1 = (cc1 & 7) << 4;
    const int ar    = rg * 16 + lrow;
    const int abase = AOFF + ar * 256;
    const int as    = ar & 7;

    int rout[4];
    #pragma unroll
    for (int reg = 0; reg < 4; ++reg) {
        int ri = rowBase + rg * 16 + (lane >> 4) * 4 + reg;
        if (ri > n - 1) ri = n - 1;
        rout[reg] = perm[ri];
    }

    #pragma unroll
    for (int h = 0; h < HALVES; ++h) {
        if (h > 0) {
            __syncthreads();
            const char* wsrc = (const char*)(Wsz + (size_t)h * 64 * 256);
            #pragma unroll
            for (int i = 0; i < 4; ++i) {
                const int off = (i * 512 + tid) * 16;
                __builtin_amdgcn_global_load_lds(
                    (const __attribute__((address_space(1))) unsigned int*)(wsrc + off),
                    (__attribute__((address_space(3))) unsigned int*)(smem + off),
                    16, 0, 0);
            }
            __syncthreads();
        }

        f32x4 acc0 = (f32x4){0.f, 0.f, 0.f, 0.f};
        f32x4 acc1 = (f32x4){0.f, 0.f, 0.f, 0.f};

        #pragma unroll
        for (int ks = 0; ks < 8; ++ks) {
            bf16x8 a;
            if (ks < 4)
                a = *(const bf16x8*)(smem + abase + (((ks * 4 + (lane >> 4)) ^ as) << 4));
            else
                a = xr[ks - 4];
            bf16x8 b0 = *(const bf16x8*)(smem + ((cb0 + (ks << 6)) ^ xm0));
            bf16x8 b1 = *(const bf16x8*)(smem + ((cb1 + (ks << 6)) ^ xm1));
            acc0 = __builtin_amdgcn_mfma_f32_16x16x32_bf16(a, b0, acc0, 0, 0, 0);
            acc1 = __builtin_amdgcn_mfma_f32_16x16x32_bf16(a, b1, acc1, 0, 0, 0);
        }

        #pragma unroll
        for (int nf = 0; nf < 2; ++nf) {
            const f32x4 av = nf ? acc1 : acc0;
            const int c = h * 64 + cg * 32 + nf * 16 + lrow;
            const float bv = bias[c];
            #pragma unroll
            for (int reg = 0; reg < 4; ++reg) {
                const int r = rout[reg];
                float hv = av[reg] + bv;
                if (RELU) hv = fmaxf(hv, 0.f);
                if (FINAL) {
                    outF[(size_t)r * NOUT + c] = hv;
                } else {
                    outC[(size_t)r * RS + c] = f2bf(hv);
                    outQ[(size_t)r * NFEAT + c] =
                        (unsigned char)(__builtin_amdgcn_cvt_pk_fp8_f32(hv, hv, 0, false) & 0xFF);
                }
            }
        }
    }
}

extern "C" void kernel_launch(void* const* d_in, const int* in_sizes, int n_in,
                              void* d_out, int out_size, void* d_ws, size_t ws_size,
                              hipStream_t stream) {
    const float* x   = (const float*)d_in[0];
    const int*   ei  = (const int*)d_in[1];
    const float* Wl0 = (const float*)d_in[2];
    const float* Wr0 = (const float*)d_in[3];
    const float* b0  = (const float*)d_in[4];
    const float* Wl1 = (const float*)d_in[5];
    const float* Wr1 = (const float*)d_in[6];
    const float* b1  = (const float*)d_in[7];
    const float* Wl2 = (const float*)d_in[8];
    const float* Wr2 = (const float*)d_in[9];
    const float* b2  = (const float*)d_in[10];

    const int nN = in_sizes[0] / NFEAT;       // 50000
    const int nE = in_sizes[1] / 2;           // 800000
    const int* src = ei;
    const int* dst = ei + nE;

    char* ws = (char*)d_ws;
    size_t off = 0;
    auto take = [&](size_t bytes) { char* p = ws + off; off += (bytes + 255) & ~(size_t)255; return p; };
    int*   cnt      = (int*)  take((size_t)nN * 4);
    int*   row_ptr  = (int*)  take((size_t)(nN + 1) * 4);
    int*   col_idx  = (int*)  take((size_t)nE * 4);
    float* inv_deg  = (float*)take((size_t)nN * 4);
    int*   blockSum = (int*)  take(256 * 4);
    int*   degHist  = (int*)  take(256 * 4);
    int*   perm     = (int*)  take((size_t)nN * 4);
    const size_t plane  = (size_t)nN * RS * 2;            // 12.8 MB bf16
    const size_t qplane = (size_t)nN * NFEAT;             // 6.4 MB fp8
    unsigned short* xc0  = (unsigned short*)take(plane);
    unsigned short* xc1  = (unsigned short*)take(plane);
    unsigned char*  xq0  = (unsigned char*) take(qplane);
    unsigned char*  xq1  = (unsigned char*) take(qplane);
    unsigned short* Wsz0 = (unsigned short*)take(128 * 256 * 2);
    unsigned short* Wsz1 = (unsigned short*)take(128 * 256 * 2);
    unsigned short* Wsz2 = (unsigned short*)take(64 * 256 * 2);
    (void)ws_size; (void)n_in; (void)out_size;

    const int scanBlocks = (nN + 255) / 256;
    const int sliceN = (nN + 7) / 8;

    // prep: xconv + wconv x3 + zero(cnt, degHist) in one launch
    const int prepTotal = nN * 32 + 81920 + nN + 256;
    prep_kernel<<<(prepTotal + 255) / 256, 256, 0, stream>>>(
        x, xc0, xq0, Wl0, Wr0, Wl1, Wr1, Wl2, Wr2, Wsz0, Wsz1, Wsz2, cnt, degHist, nN);

    // CSR build (XCD-sliced hist/fill) + degree-sort permutation (heavy-first)
    hist_kernel<<<2048, 256, 0, stream>>>(dst, cnt, nE, sliceN);
    blocksum_kernel<<<scanBlocks, 256, 0, stream>>>(cnt, blockSum, nN);
    scan_write_kernel<<<scanBlocks, 256, 0, stream>>>(cnt, blockSum, row_ptr, inv_deg, degHist, nN);
    fill_kernel<<<2048, 256, 0, stream>>>(src, dst, cnt, col_idx, nE, sliceN);
    bin_scan_kernel<<<1, 256, 0, stream>>>(degHist);
    scatter_kernel<<<scanBlocks, 256, 0, stream>>>(row_ptr, degHist, perm, nN);

    const int layerGrid = (nN + 63) / 64;     // 782

    // layer 0: x -> h0
    layer_kernel<128, true, false><<<layerGrid, 512, 0, stream>>>(
        xq0, xc0, row_ptr, col_idx, inv_deg, perm, Wsz0, b0, nullptr, xc1, xq1, nN);
    // layer 1: h0 -> h1
    layer_kernel<128, true, false><<<layerGrid, 512, 0, stream>>>(
        xq1, xc1, row_ptr, col_idx, inv_deg, perm, Wsz1, b1, nullptr, xc0, xq0, nN);
    // layer 2: h1 -> out (fp32)
    layer_kernel<64, false, true><<<layerGrid, 512, 0, stream>>>(
        xq0, xc0, row_ptr, col_idx, inv_deg, perm, Wsz2, b2, (float*)d_out, nullptr, nullptr, nN);
}

// Round 21
// 203.064 us; speedup vs baseline: 1.3591x; 1.3591x over previous
//
#include <hip/hip_runtime.h>

#define NFEAT 128
#define RS 128   // bf16 plane row stride in shorts

using bf16x8 = __attribute__((ext_vector_type(8))) short;
using f32x4  = __attribute__((ext_vector_type(4))) float;
using f32x2  = __attribute__((ext_vector_type(2))) float;

__device__ __forceinline__ float bf2f(unsigned short u) {
    union { unsigned int i; float f; } v; v.i = ((unsigned int)u) << 16; return v.f;
}
__device__ __forceinline__ unsigned short f2bf(float f) {      // RNE
    union { float f; unsigned int i; } v; v.f = f;
    unsigned int i = v.i;
    return (unsigned short)((i + 0x7FFFu + ((i >> 16) & 1u)) >> 16);
}
__device__ __forceinline__ unsigned int f4_to_fp8x4(float f0, float f1, float f2, float f3) {
    int p = __builtin_amdgcn_cvt_pk_fp8_f32(f0, f1, 0, false);
    p     = __builtin_amdgcn_cvt_pk_fp8_f32(f2, f3, p, true);
    return (unsigned int)p;
}

// ---------------- CSR build (XCD-sliced hist/fill) ----------------

__global__ void hist_kernel(const int* __restrict__ dst, int* __restrict__ cnt,
                            int nE, int sliceN) {
    const int slice = blockIdx.x & 7;
    const int lo = slice * sliceN, hi = lo + sliceN;
    const int nb = gridDim.x >> 3;
    const int bs = blockIdx.x >> 3;
    for (int i = bs * 256 + threadIdx.x; i < nE; i += nb * 256) {
        int d = dst[i];
        if (d >= lo && d < hi) atomicAdd(&cnt[d], 1);
    }
}

__global__ void fill_kernel(const int* __restrict__ src, const int* __restrict__ dst,
                            int* __restrict__ cnt, int* __restrict__ col_idx,
                            int nE, int sliceN) {
    const int slice = blockIdx.x & 7;
    const int lo = slice * sliceN, hi = lo + sliceN;
    const int nb = gridDim.x >> 3;
    const int bs = blockIdx.x >> 3;
    for (int i = bs * 256 + threadIdx.x; i < nE; i += nb * 256) {
        int d = dst[i];
        int s = src[i];
        if (d >= lo && d < hi) {
            int pos = atomicAdd(&cnt[d], 1);
            col_idx[pos] = s;
        }
    }
}

__global__ void blocksum_kernel(const int* __restrict__ cnt, int* __restrict__ blockSum, int n) {
    int i = blockIdx.x * 256 + threadIdx.x;
    int d = (i < n) ? cnt[i] : 0;
    int lane = threadIdx.x & 63, wid = threadIdx.x >> 6;
    __shared__ int ws[4];
    int v = d;
    for (int off = 32; off; off >>= 1) v += __shfl_down(v, off);
    if (lane == 0) ws[wid] = v;
    __syncthreads();
    if (threadIdx.x == 0) blockSum[blockIdx.x] = ws[0] + ws[1] + ws[2] + ws[3];
}

// degree histogram via per-block LDS aggregation (round-16 lesson)
__global__ void scan_write_kernel(int* __restrict__ cnt, const int* __restrict__ blockSum,
                                  int* __restrict__ row_ptr, float* __restrict__ inv_deg,
                                  int* __restrict__ degHist, int n) {
    const int b = blockIdx.x, tid = threadIdx.x;
    const int lane = tid & 63, wid = tid >> 6;
    __shared__ int wsA[4];
    __shared__ int wsB[4];
    __shared__ int lhist[256];
    lhist[tid] = 0;
    int v = (tid < b) ? blockSum[tid] : 0;
    for (int off = 32; off; off >>= 1) v += __shfl_down(v, off);
    if (lane == 0) wsA[wid] = v;
    int i = b * 256 + tid;
    int d = (i < n) ? cnt[i] : 0;
    int s = d;
    for (int off = 1; off < 64; off <<= 1) {
        int t = __shfl_up(s, off);
        if (lane >= off) s += t;
    }
    if (lane == 63) wsB[wid] = s;
    __syncthreads();
    int blockOff = wsA[0] + wsA[1] + wsA[2] + wsA[3];
    int wOff = 0;
    for (int w = 0; w < wid; ++w) wOff += wsB[w];
    int excl = blockOff + wOff + s - d;
    if (i < n) {
        row_ptr[i] = excl;
        cnt[i]     = excl;
        inv_deg[i] = 1.0f / (float)(d > 1 ? d : 1);
        atomicAdd(&lhist[d > 255 ? 255 : d], 1);
    }
    if (i == n) row_ptr[n] = excl;
    __syncthreads();
    if (lhist[tid] > 0) atomicAdd(&degHist[tid], lhist[tid]);
}

// DESCENDING-degree bin cursors: heavy nodes first (LPT scheduling, round-19 win)
__global__ void bin_scan_kernel(int* __restrict__ dh) {
    const int tid = threadIdx.x, lane = tid & 63, w = tid >> 6;
    __shared__ int ws[4];
    const int idx = 255 - tid;          // process bins in reverse
    int v = dh[idx];
    int s = v;
    for (int off = 1; off < 64; off <<= 1) {
        int t = __shfl_up(s, off);
        if (lane >= off) s += t;
    }
    if (lane == 63) ws[w] = s;
    __syncthreads();
    int woff = 0;
    for (int i = 0; i < w; ++i) woff += ws[i];
    dh[idx] = woff + s - v;             // = count of nodes with degree > idx
}

// degree-sorted permutation, LDS-aggregated
__global__ void scatter_kernel(const int* __restrict__ row_ptr, int* __restrict__ cursor,
                               int* __restrict__ perm, int n) {
    __shared__ int lhist[256];
    __shared__ int lbase[256];
    const int tid = threadIdx.x;
    lhist[tid] = 0;
    __syncthreads();
    int i = blockIdx.x * 256 + tid;
    int d = 0, lr = 0;
    if (i < n) {
        d = row_ptr[i + 1] - row_ptr[i];
        if (d > 255) d = 255;
        lr = atomicAdd(&lhist[d], 1);
    }
    __syncthreads();
    if (lhist[tid] > 0) lbase[tid] = atomicAdd(&cursor[tid], lhist[tid]);
    __syncthreads();
    if (i < n) perm[lbase[d] + lr] = i;
}

// ---------------- fused prep: xconv + all wconv + zero(cnt,degHist) ----------------

__global__ void prep_kernel(const float* __restrict__ x,
                            unsigned short* __restrict__ xc, unsigned char* __restrict__ xq,
                            const float* __restrict__ Wl0, const float* __restrict__ Wr0,
                            const float* __restrict__ Wl1, const float* __restrict__ Wr1,
                            const float* __restrict__ Wl2, const float* __restrict__ Wr2,
                            unsigned short* __restrict__ Wsz0,
                            unsigned short* __restrict__ Wsz1,
                            unsigned short* __restrict__ Wsz2,
                            int* __restrict__ cnt, int* __restrict__ degHist, int n) {
    int idx = blockIdx.x * 256 + threadIdx.x;
    const int R0 = n * 32;
    if (idx < R0) {
        int node = idx >> 5, fb = (idx & 31) * 4;
        float4 v = *(const float4*)(x + (size_t)node * NFEAT + fb);
        uint2 hw;
        hw.x = (unsigned int)f2bf(v.x) | ((unsigned int)f2bf(v.y) << 16);
        hw.y = (unsigned int)f2bf(v.z) | ((unsigned int)f2bf(v.w) << 16);
        *(uint2*)(xc + (size_t)node * RS + fb) = hw;
        *(unsigned int*)(xq + (size_t)node * NFEAT + fb) = f4_to_fp8x4(v.x, v.y, v.z, v.w);
        return;
    }
    idx -= R0;
    if (idx < 81920) {
        const float* Wl; const float* Wr; unsigned short* Wsz; int nout; int li;
        if (idx < 32768)      { Wl = Wl0; Wr = Wr0; Wsz = Wsz0; nout = 128; li = idx; }
        else if (idx < 65536) { Wl = Wl1; Wr = Wr1; Wsz = Wsz1; nout = 128; li = idx - 32768; }
        else                  { Wl = Wl2; Wr = Wr2; Wsz = Wsz2; nout = 64;  li = idx - 65536; }
        int c = li >> 8, k = li & 255;
        float f = (k < 128) ? Wl[k * nout + c] : Wr[(k - 128) * nout + c];
        Wsz[c * 256 + (k ^ ((c & 7) << 3))] = f2bf(f);
        return;
    }
    idx -= 81920;
    if (idx < n) { cnt[idx] = 0; return; }
    idx -= n;
    if (idx < 256) degHist[idx] = 0;
}

// ---------------- fused layer: gather-mean (fp8) -> LDS -> MFMA GEMM ----------------
// Round-21: gather identical to round-19 (the 194.8us best; round-20's asm
// batch spilled -- WRITE_SIZE 119MB scratch -- and is abandoned). Change: W-LDS
// shrunk to a QUARTER tile (32 cols x 256 k = 16KB) -> total LDS 32KB -> 4
// blocks/CU = 32 waves/CU (hardware cap) vs 3 blocks/24 waves: +33% wave-level
// concurrency for the latency-bound gather phase. GEMM runs 4 stages of 32
// cols (wave = 16 rows x 16 cols per stage; same 32 MFMA/wave total).

template<int NOUT, bool RELU, bool FINAL>
__global__ __launch_bounds__(512, 4) void layer_kernel(
    const unsigned char* __restrict__ xq, const unsigned short* __restrict__ xc,
    const int* __restrict__ row_ptr, const int* __restrict__ col_idx,
    const float* __restrict__ inv_deg, const int* __restrict__ perm,
    const unsigned short* __restrict__ Wsz, const float* __restrict__ bias,
    float* __restrict__ outF, unsigned short* __restrict__ outC,
    unsigned char* __restrict__ outQ, int n)
{
    constexpr int STAGES = NOUT / 32;
    constexpr int AOFF = 16384;
    __shared__ char smem[16384 + 16384];   // W quarter (16KB) | A tile (16KB)
    const int tid  = threadIdx.x;
    const int lane = tid & 63;
    const int wid  = tid >> 6;             // 0..7
    const int rowBase = blockIdx.x * 64;

    // ---- stage W quarter 0 via global_load_lds (lane-linear) ----
    {
        const char* wsrc = (const char*)Wsz;
        #pragma unroll
        for (int i = 0; i < 2; ++i) {
            const int off = (i * 512 + tid) * 16;
            __builtin_amdgcn_global_load_lds(
                (const __attribute__((address_space(1))) unsigned int*)(wsrc + off),
                (__attribute__((address_space(3))) unsigned int*)(smem + off),
                16, 0, 0);
        }
    }

    // ---- x-side prefetch (ks 4..7) for this thread's GEMM rows ----
    const int lrow = lane & 15;
    const int lk   = (lane >> 4) * 8;
    const int rg   = wid >> 1;             // row group (16 rows each)
    const int cg   = wid & 1;              // col group (16 cols within stage)
    int ri0 = rowBase + rg * 16 + lrow; if (ri0 > n - 1) ri0 = n - 1;
    const int xnode = perm[ri0];
    const unsigned short* Xr = xc + (size_t)xnode * RS;
    bf16x8 xr[4];
    #pragma unroll
    for (int ks = 0; ks < 4; ++ks) xr[ks] = *(const bf16x8*)(Xr + ks * 32 + lk);
    __builtin_amdgcn_sched_barrier(0);

    // ---- gather: 64 nodes (degree-sorted), 8 lanes/node, fp8 rows ----
    {
        const int l    = tid & 7;
        const int nd   = tid >> 3;         // 0..63 block-local
        int pidx = rowBase + nd; if (pidx > n - 1) pidx = n - 1;
        const int node = perm[pidx];
        int beg = row_ptr[node], end = row_ptr[node + 1];
        float a[2][16];
        #pragma unroll
        for (int u = 0; u < 2; ++u)
            #pragma unroll
            for (int j = 0; j < 16; ++j) a[u][j] = 0.f;
        auto acc16 = [&](float* A, uint4 v) {
            f32x2 d;
            d = __builtin_amdgcn_cvt_pk_f32_fp8(v.x, false); A[0]  += d[0]; A[1]  += d[1];
            d = __builtin_amdgcn_cvt_pk_f32_fp8(v.x, true);  A[2]  += d[0]; A[3]  += d[1];
            d = __builtin_amdgcn_cvt_pk_f32_fp8(v.y, false); A[4]  += d[0]; A[5]  += d[1];
            d = __builtin_amdgcn_cvt_pk_f32_fp8(v.y, true);  A[6]  += d[0]; A[7]  += d[1];
            d = __builtin_amdgcn_cvt_pk_f32_fp8(v.z, false); A[8]  += d[0]; A[9]  += d[1];
            d = __builtin_amdgcn_cvt_pk_f32_fp8(v.z, true);  A[10] += d[0]; A[11] += d[1];
            d = __builtin_amdgcn_cvt_pk_f32_fp8(v.w, false); A[12] += d[0]; A[13] += d[1];
            d = __builtin_amdgcn_cvt_pk_f32_fp8(v.w, true);  A[14] += d[0]; A[15] += d[1];
        };
        int e = beg;
        for (; e + 8 <= end; e += 8) {
            uint4 v[8];
            #pragma unroll
            for (int u = 0; u < 8; ++u) {
                int s = col_idx[e + u];
                v[u] = *(const uint4*)(xq + (size_t)s * NFEAT + l * 16);
            }
            #pragma unroll
            for (int u = 0; u < 8; ++u) acc16(a[u & 1], v[u]);
        }
        for (; e < end; ++e) {
            int s = col_idx[e];
            uint4 v = *(const uint4*)(xq + (size_t)s * NFEAT + l * 16);
            acc16(a[0], v);
        }
        float sc = inv_deg[node];
        unsigned short hs[16];
        #pragma unroll
        for (int j = 0; j < 16; ++j)
            hs[j] = f2bf((a[0][j] + a[1][j]) * sc);
        uint4 h0, h1;
        h0.x = (unsigned int)hs[0]  | ((unsigned int)hs[1]  << 16);
        h0.y = (unsigned int)hs[2]  | ((unsigned int)hs[3]  << 16);
        h0.z = (unsigned int)hs[4]  | ((unsigned int)hs[5]  << 16);
        h0.w = (unsigned int)hs[6]  | ((unsigned int)hs[7]  << 16);
        h1.x = (unsigned int)hs[8]  | ((unsigned int)hs[9]  << 16);
        h1.y = (unsigned int)hs[10] | ((unsigned int)hs[11] << 16);
        h1.z = (unsigned int)hs[12] | ((unsigned int)hs[13] << 16);
        h1.w = (unsigned int)hs[14] | ((unsigned int)hs[15] << 16);
        const int s_ = nd & 7;
        char* arow = smem + AOFF + nd * 256;
        *(uint4*)(arow + (((2 * l)     ^ s_) << 4)) = h0;
        *(uint4*)(arow + (((2 * l + 1) ^ s_) << 4)) = h1;
    }

    __syncthreads();                       // W quarter0 + A tile + xr all resident

    // B-frag addressing within current W quarter: cc in [0,32)
    const int cc = cg * 16 + lrow;
    const int cb = (cc << 9) + ((lane >> 4) * 16);
    const int xm = (cc & 7) << 4;
    // A-frag addressing
    const int ar    = rg * 16 + lrow;
    const int abase = AOFF + ar * 256;
    const int as    = ar & 7;

    // output row ids (true node ids via perm), 4 per thread
    int rout[4];
    #pragma unroll
    for (int reg = 0; reg < 4; ++reg) {
        int ri = rowBase + rg * 16 + (lane >> 4) * 4 + reg;
        if (ri > n - 1) ri = n - 1;
        rout[reg] = perm[ri];
    }

    #pragma unroll
    for (int s = 0; s < STAGES; ++s) {
        if (s > 0) {
            __syncthreads();               // prior stage reads done before overwrite
            const char* wsrc = (const char*)(Wsz + (size_t)s * 32 * 256);
            #pragma unroll
            for (int i = 0; i < 2; ++i) {
                const int off = (i * 512 + tid) * 16;
                __builtin_amdgcn_global_load_lds(
                    (const __attribute__((address_space(1))) unsigned int*)(wsrc + off),
                    (__attribute__((address_space(3))) unsigned int*)(smem + off),
                    16, 0, 0);
            }
            __syncthreads();               // W quarter s resident
        }

        f32x4 acc = (f32x4){0.f, 0.f, 0.f, 0.f};
        #pragma unroll
        for (int ks = 0; ks < 8; ++ks) {
            bf16x8 a;
            if (ks < 4)
                a = *(const bf16x8*)(smem + abase + (((ks * 4 + (lane >> 4)) ^ as) << 4));
            else
                a = xr[ks - 4];
            bf16x8 b = *(const bf16x8*)(smem + ((cb + (ks << 6)) ^ xm));
            acc = __builtin_amdgcn_mfma_f32_16x16x32_bf16(a, b, acc, 0, 0, 0);
        }

        // epilogue for this stage (16 cols per wave)
        const int c = s * 32 + cg * 16 + lrow;
        const float bv = bias[c];
        #pragma unroll
        for (int reg = 0; reg < 4; ++reg) {
            const int r = rout[reg];
            float hv = acc[reg] + bv;
            if (RELU) hv = fmaxf(hv, 0.f);
            if (FINAL) {
                outF[(size_t)r * NOUT + c] = hv;
            } else {
                outC[(size_t)r * RS + c] = f2bf(hv);
                outQ[(size_t)r * NFEAT + c] =
                    (unsigned char)(__builtin_amdgcn_cvt_pk_fp8_f32(hv, hv, 0, false) & 0xFF);
            }
        }
    }
}

extern "C" void kernel_launch(void* const* d_in, const int* in_sizes, int n_in,
                              void* d_out, int out_size, void* d_ws, size_t ws_size,
                              hipStream_t stream) {
    const float* x   = (const float*)d_in[0];
    const int*   ei  = (const int*)d_in[1];
    const float* Wl0 = (const float*)d_in[2];
    const float* Wr0 = (const float*)d_in[3];
    const float* b0  = (const float*)d_in[4];
    const float* Wl1 = (const float*)d_in[5];
    const float* Wr1 = (const float*)d_in[6];
    const float* b1  = (const float*)d_in[7];
    const float* Wl2 = (const float*)d_in[8];
    const float* Wr2 = (const float*)d_in[9];
    const float* b2  = (const float*)d_in[10];

    const int nN = in_sizes[0] / NFEAT;       // 50000
    const int nE = in_sizes[1] / 2;           // 800000
    const int* src = ei;
    const int* dst = ei + nE;

    char* ws = (char*)d_ws;
    size_t off = 0;
    auto take = [&](size_t bytes) { char* p = ws + off; off += (bytes + 255) & ~(size_t)255; return p; };
    int*   cnt      = (int*)  take((size_t)nN * 4);
    int*   row_ptr  = (int*)  take((size_t)(nN + 1) * 4);
    int*   col_idx  = (int*)  take((size_t)nE * 4);
    float* inv_deg  = (float*)take((size_t)nN * 4);
    int*   blockSum = (int*)  take(256 * 4);
    int*   degHist  = (int*)  take(256 * 4);
    int*   perm     = (int*)  take((size_t)nN * 4);
    const size_t plane  = (size_t)nN * RS * 2;            // 12.8 MB bf16
    const size_t qplane = (size_t)nN * NFEAT;             // 6.4 MB fp8
    unsigned short* xc0  = (unsigned short*)take(plane);
    unsigned short* xc1  = (unsigned short*)take(plane);
    unsigned char*  xq0  = (unsigned char*) take(qplane);
    unsigned char*  xq1  = (unsigned char*) take(qplane);
    unsigned short* Wsz0 = (unsigned short*)take(128 * 256 * 2);
    unsigned short* Wsz1 = (unsigned short*)take(128 * 256 * 2);
    unsigned short* Wsz2 = (unsigned short*)take(64 * 256 * 2);
    (void)ws_size; (void)n_in; (void)out_size;

    const int scanBlocks = (nN + 255) / 256;
    const int sliceN = (nN + 7) / 8;

    // prep: xconv + wconv x3 + zero(cnt, degHist) in one launch
    const int prepTotal = nN * 32 + 81920 + nN + 256;
    prep_kernel<<<(prepTotal + 255) / 256, 256, 0, stream>>>(
        x, xc0, xq0, Wl0, Wr0, Wl1, Wr1, Wl2, Wr2, Wsz0, Wsz1, Wsz2, cnt, degHist, nN);

    // CSR build (XCD-sliced hist/fill) + degree-sort permutation (heavy-first)
    hist_kernel<<<2048, 256, 0, stream>>>(dst, cnt, nE, sliceN);
    blocksum_kernel<<<scanBlocks, 256, 0, stream>>>(cnt, blockSum, nN);
    scan_write_kernel<<<scanBlocks, 256, 0, stream>>>(cnt, blockSum, row_ptr, inv_deg, degHist, nN);
    fill_kernel<<<2048, 256, 0, stream>>>(src, dst, cnt, col_idx, nE, sliceN);
    bin_scan_kernel<<<1, 256, 0, stream>>>(degHist);
    scatter_kernel<<<scanBlocks, 256, 0, stream>>>(row_ptr, degHist, perm, nN);

    const int layerGrid = (nN + 63) / 64;     // 782

    // layer 0: x -> h0
    layer_kernel<128, true, false><<<layerGrid, 512, 0, stream>>>(
        xq0, xc0, row_ptr, col_idx, inv_deg, perm, Wsz0, b0, nullptr, xc1, xq1, nN);
    // layer 1: h0 -> h1
    layer_kernel<128, true, false><<<layerGrid, 512, 0, stream>>>(
        xq1, xc1, row_ptr, col_idx, inv_deg, perm, Wsz1, b1, nullptr, xc0, xq0, nN);
    // layer 2: h1 -> out (fp32)
    layer_kernel<64, false, true><<<layerGrid, 512, 0, stream>>>(
        xq0, xc0, row_ptr, col_idx, inv_deg, perm, Wsz2, b2, (float*)d_out, nullptr, nullptr, nN);
}

// Round 22
// 176.018 us; speedup vs baseline: 1.5680x; 1.1537x over previous
//
#include <hip/hip_runtime.h>

#define NFEAT 128
#define RS 128   // bf16 plane row stride in shorts

using bf16x8 = __attribute__((ext_vector_type(8))) short;
using f32x4  = __attribute__((ext_vector_type(4))) float;
using f32x2  = __attribute__((ext_vector_type(2))) float;

__device__ __forceinline__ float bf2f(unsigned short u) {
    union { unsigned int i; float f; } v; v.i = ((unsigned int)u) << 16; return v.f;
}
__device__ __forceinline__ unsigned short f2bf(float f) {      // RNE
    union { float f; unsigned int i; } v; v.f = f;
    unsigned int i = v.i;
    return (unsigned short)((i + 0x7FFFu + ((i >> 16) & 1u)) >> 16);
}
__device__ __forceinline__ unsigned int f4_to_fp8x4(float f0, float f1, float f2, float f3) {
    int p = __builtin_amdgcn_cvt_pk_fp8_f32(f0, f1, 0, false);
    p     = __builtin_amdgcn_cvt_pk_fp8_f32(f2, f3, p, true);
    return (unsigned int)p;
}

// ---------------- CSR build (XCD-sliced hist/fill) ----------------

__global__ void hist_kernel(const int* __restrict__ dst, int* __restrict__ cnt,
                            int nE, int sliceN) {
    const int slice = blockIdx.x & 7;
    const int lo = slice * sliceN, hi = lo + sliceN;
    const int nb = gridDim.x >> 3;
    const int bs = blockIdx.x >> 3;
    for (int i = bs * 256 + threadIdx.x; i < nE; i += nb * 256) {
        int d = dst[i];
        if (d >= lo && d < hi) atomicAdd(&cnt[d], 1);
    }
}

__global__ void fill_kernel(const int* __restrict__ src, const int* __restrict__ dst,
                            int* __restrict__ cnt, int* __restrict__ col_idx,
                            int nE, int sliceN) {
    const int slice = blockIdx.x & 7;
    const int lo = slice * sliceN, hi = lo + sliceN;
    const int nb = gridDim.x >> 3;
    const int bs = blockIdx.x >> 3;
    for (int i = bs * 256 + threadIdx.x; i < nE; i += nb * 256) {
        int d = dst[i];
        int s = src[i];
        if (d >= lo && d < hi) {
            int pos = atomicAdd(&cnt[d], 1);
            col_idx[pos] = s;
        }
    }
}

__global__ void blocksum_kernel(const int* __restrict__ cnt, int* __restrict__ blockSum, int n) {
    int i = blockIdx.x * 256 + threadIdx.x;
    int d = (i < n) ? cnt[i] : 0;
    int lane = threadIdx.x & 63, wid = threadIdx.x >> 6;
    __shared__ int ws[4];
    int v = d;
    for (int off = 32; off; off >>= 1) v += __shfl_down(v, off);
    if (lane == 0) ws[wid] = v;
    __syncthreads();
    if (threadIdx.x == 0) blockSum[blockIdx.x] = ws[0] + ws[1] + ws[2] + ws[3];
}

// degree histogram via per-block LDS aggregation (round-16 lesson)
__global__ void scan_write_kernel(int* __restrict__ cnt, const int* __restrict__ blockSum,
                                  int* __restrict__ row_ptr, float* __restrict__ inv_deg,
                                  int* __restrict__ degHist, int n) {
    const int b = blockIdx.x, tid = threadIdx.x;
    const int lane = tid & 63, wid = tid >> 6;
    __shared__ int wsA[4];
    __shared__ int wsB[4];
    __shared__ int lhist[256];
    lhist[tid] = 0;
    int v = (tid < b) ? blockSum[tid] : 0;
    for (int off = 32; off; off >>= 1) v += __shfl_down(v, off);
    if (lane == 0) wsA[wid] = v;
    int i = b * 256 + tid;
    int d = (i < n) ? cnt[i] : 0;
    int s = d;
    for (int off = 1; off < 64; off <<= 1) {
        int t = __shfl_up(s, off);
        if (lane >= off) s += t;
    }
    if (lane == 63) wsB[wid] = s;
    __syncthreads();
    int blockOff = wsA[0] + wsA[1] + wsA[2] + wsA[3];
    int wOff = 0;
    for (int w = 0; w < wid; ++w) wOff += wsB[w];
    int excl = blockOff + wOff + s - d;
    if (i < n) {
        row_ptr[i] = excl;
        cnt[i]     = excl;
        inv_deg[i] = 1.0f / (float)(d > 1 ? d : 1);
        atomicAdd(&lhist[d > 255 ? 255 : d], 1);
    }
    if (i == n) row_ptr[n] = excl;
    __syncthreads();
    if (lhist[tid] > 0) atomicAdd(&degHist[tid], lhist[tid]);
}

// DESCENDING-degree bin cursors: heavy nodes first (LPT scheduling, round-19 win)
__global__ void bin_scan_kernel(int* __restrict__ dh) {
    const int tid = threadIdx.x, lane = tid & 63, w = tid >> 6;
    __shared__ int ws[4];
    const int idx = 255 - tid;          // process bins in reverse
    int v = dh[idx];
    int s = v;
    for (int off = 1; off < 64; off <<= 1) {
        int t = __shfl_up(s, off);
        if (lane >= off) s += t;
    }
    if (lane == 63) ws[w] = s;
    __syncthreads();
    int woff = 0;
    for (int i = 0; i < w; ++i) woff += ws[i];
    dh[idx] = woff + s - v;             // = count of nodes with degree > idx
}

// degree-sorted permutation, LDS-aggregated
__global__ void scatter_kernel(const int* __restrict__ row_ptr, int* __restrict__ cursor,
                               int* __restrict__ perm, int n) {
    __shared__ int lhist[256];
    __shared__ int lbase[256];
    const int tid = threadIdx.x;
    lhist[tid] = 0;
    __syncthreads();
    int i = blockIdx.x * 256 + tid;
    int d = 0, lr = 0;
    if (i < n) {
        d = row_ptr[i + 1] - row_ptr[i];
        if (d > 255) d = 255;
        lr = atomicAdd(&lhist[d], 1);
    }
    __syncthreads();
    if (lhist[tid] > 0) lbase[tid] = atomicAdd(&cursor[tid], lhist[tid]);
    __syncthreads();
    if (i < n) perm[lbase[d] + lr] = i;
}

// ---------------- fused prep: xconv + all wconv + zero(cnt,degHist) ----------------

__global__ void prep_kernel(const float* __restrict__ x,
                            unsigned short* __restrict__ xc, unsigned char* __restrict__ xq,
                            const float* __restrict__ Wl0, const float* __restrict__ Wr0,
                            const float* __restrict__ Wl1, const float* __restrict__ Wr1,
                            const float* __restrict__ Wl2, const float* __restrict__ Wr2,
                            unsigned short* __restrict__ Wsz0,
                            unsigned short* __restrict__ Wsz1,
                            unsigned short* __restrict__ Wsz2,
                            int* __restrict__ cnt, int* __restrict__ degHist, int n) {
    int idx = blockIdx.x * 256 + threadIdx.x;
    const int R0 = n * 32;
    if (idx < R0) {
        int node = idx >> 5, fb = (idx & 31) * 4;
        float4 v = *(const float4*)(x + (size_t)node * NFEAT + fb);
        uint2 hw;
        hw.x = (unsigned int)f2bf(v.x) | ((unsigned int)f2bf(v.y) << 16);
        hw.y = (unsigned int)f2bf(v.z) | ((unsigned int)f2bf(v.w) << 16);
        *(uint2*)(xc + (size_t)node * RS + fb) = hw;
        *(unsigned int*)(xq + (size_t)node * NFEAT + fb) = f4_to_fp8x4(v.x, v.y, v.z, v.w);
        return;
    }
    idx -= R0;
    if (idx < 81920) {
        const float* Wl; const float* Wr; unsigned short* Wsz; int nout; int li;
        if (idx < 32768)      { Wl = Wl0; Wr = Wr0; Wsz = Wsz0; nout = 128; li = idx; }
        else if (idx < 65536) { Wl = Wl1; Wr = Wr1; Wsz = Wsz1; nout = 128; li = idx - 32768; }
        else                  { Wl = Wl2; Wr = Wr2; Wsz = Wsz2; nout = 64;  li = idx - 65536; }
        int c = li >> 8, k = li & 255;
        float f = (k < 128) ? Wl[k * nout + c] : Wr[(k - 128) * nout + c];
        Wsz[c * 256 + (k ^ ((c & 7) << 3))] = f2bf(f);
        return;
    }
    idx -= 81920;
    if (idx < n) { cnt[idx] = 0; return; }
    idx -= n;
    if (idx < 256) degHist[idx] = 0;
}

// ---------------- fused layer: gather-mean (fp8) -> LDS -> MFMA GEMM ----------------
// Round-22 = round-19 structure (the 194.8us best) with a REGISTER-DIET gather:
//   - unroll 4 + single a[16] accumulator (live regs during gather ~40 < 64,
//     so the 4-deep load batch can actually pipeline; rounds 17/18/20 proved
//     the 64-VGPR allocation is immovable and unroll-8 cannot fit in it),
//   - xr x-side prefetch moved AFTER the gather (frees 16 regs during gather;
//     its latency hides under the A-tile LDS-writes + barrier).

template<int NOUT, bool RELU, bool FINAL>
__global__ __launch_bounds__(512, 4) void layer_kernel(
    const unsigned char* __restrict__ xq, const unsigned short* __restrict__ xc,
    const int* __restrict__ row_ptr, const int* __restrict__ col_idx,
    const float* __restrict__ inv_deg, const int* __restrict__ perm,
    const unsigned short* __restrict__ Wsz, const float* __restrict__ bias,
    float* __restrict__ outF, unsigned short* __restrict__ outC,
    unsigned char* __restrict__ outQ, int n)
{
    constexpr int HALVES = NOUT / 64;
    constexpr int AOFF = 32768;
    __shared__ char smem[32768 + 16384];   // W half (32KB) | A tile (16KB)
    const int tid  = threadIdx.x;
    const int lane = tid & 63;
    const int wid  = tid >> 6;             // 0..7
    const int rowBase = blockIdx.x * 64;

    // ---- stage W half 0 via global_load_lds (lane-linear) ----
    {
        const char* wsrc = (const char*)Wsz;
        #pragma unroll
        for (int i = 0; i < 4; ++i) {
            const int off = (i * 512 + tid) * 16;
            __builtin_amdgcn_global_load_lds(
                (const __attribute__((address_space(1))) unsigned int*)(wsrc + off),
                (__attribute__((address_space(3))) unsigned int*)(smem + off),
                16, 0, 0);
        }
    }

    const int lrow = lane & 15;
    const int lk   = (lane >> 4) * 8;
    const int rg   = wid >> 1;             // row group (16 rows each)
    const int cg   = wid & 1;              // col group (32 cols each)

    // ---- gather: 64 nodes (degree-sorted), 8 lanes/node, fp8 rows ----
    {
        const int l    = tid & 7;
        const int nd   = tid >> 3;         // 0..63 block-local
        int pidx = rowBase + nd; if (pidx > n - 1) pidx = n - 1;
        const int node = perm[pidx];
        int beg = row_ptr[node], end = row_ptr[node + 1];
        float a[16];
        #pragma unroll
        for (int j = 0; j < 16; ++j) a[j] = 0.f;
        auto acc16 = [&](float* A, uint4 v) {
            f32x2 d;
            d = __builtin_amdgcn_cvt_pk_f32_fp8(v.x, false); A[0]  += d[0]; A[1]  += d[1];
            d = __builtin_amdgcn_cvt_pk_f32_fp8(v.x, true);  A[2]  += d[0]; A[3]  += d[1];
            d = __builtin_amdgcn_cvt_pk_f32_fp8(v.y, false); A[4]  += d[0]; A[5]  += d[1];
            d = __builtin_amdgcn_cvt_pk_f32_fp8(v.y, true);  A[6]  += d[0]; A[7]  += d[1];
            d = __builtin_amdgcn_cvt_pk_f32_fp8(v.z, false); A[8]  += d[0]; A[9]  += d[1];
            d = __builtin_amdgcn_cvt_pk_f32_fp8(v.z, true);  A[10] += d[0]; A[11] += d[1];
            d = __builtin_amdgcn_cvt_pk_f32_fp8(v.w, false); A[12] += d[0]; A[13] += d[1];
            d = __builtin_amdgcn_cvt_pk_f32_fp8(v.w, true);  A[14] += d[0]; A[15] += d[1];
        };
        const unsigned char* xqb = xq + l * 16;
        int e = beg;
        for (; e + 4 <= end; e += 4) {
            uint4 v0 = *(const uint4*)(xqb + (size_t)col_idx[e + 0] * NFEAT);
            uint4 v1 = *(const uint4*)(xqb + (size_t)col_idx[e + 1] * NFEAT);
            uint4 v2 = *(const uint4*)(xqb + (size_t)col_idx[e + 2] * NFEAT);
            uint4 v3 = *(const uint4*)(xqb + (size_t)col_idx[e + 3] * NFEAT);
            acc16(a, v0); acc16(a, v1); acc16(a, v2); acc16(a, v3);
        }
        for (; e < end; ++e) {
            uint4 v = *(const uint4*)(xqb + (size_t)col_idx[e] * NFEAT);
            acc16(a, v);
        }
        float sc = inv_deg[node];
        unsigned short hs[16];
        #pragma unroll
        for (int j = 0; j < 16; ++j)
            hs[j] = f2bf(a[j] * sc);
        uint4 h0, h1;
        h0.x = (unsigned int)hs[0]  | ((unsigned int)hs[1]  << 16);
        h0.y = (unsigned int)hs[2]  | ((unsigned int)hs[3]  << 16);
        h0.z = (unsigned int)hs[4]  | ((unsigned int)hs[5]  << 16);
        h0.w = (unsigned int)hs[6]  | ((unsigned int)hs[7]  << 16);
        h1.x = (unsigned int)hs[8]  | ((unsigned int)hs[9]  << 16);
        h1.y = (unsigned int)hs[10] | ((unsigned int)hs[11] << 16);
        h1.z = (unsigned int)hs[12] | ((unsigned int)hs[13] << 16);
        h1.w = (unsigned int)hs[14] | ((unsigned int)hs[15] << 16);
        const int s_ = nd & 7;
        char* arow = smem + AOFF + nd * 256;
        *(uint4*)(arow + (((2 * l)     ^ s_) << 4)) = h0;
        *(uint4*)(arow + (((2 * l + 1) ^ s_) << 4)) = h1;
    }

    // ---- x-side prefetch (ks 4..7): AFTER gather, latency hides under barrier ----
    int ri0 = rowBase + rg * 16 + lrow; if (ri0 > n - 1) ri0 = n - 1;
    const int xnode = perm[ri0];
    const unsigned short* Xr = xc + (size_t)xnode * RS;
    bf16x8 xr[4];
    #pragma unroll
    for (int ks = 0; ks < 4; ++ks) xr[ks] = *(const bf16x8*)(Xr + ks * 32 + lk);

    __syncthreads();                       // W half0 + A tile resident

    const int cc0 = cg * 32 + lrow;
    const int cc1 = cg * 32 + 16 + lrow;
    const int cb0 = (cc0 << 9) + ((lane >> 4) * 16), xm0 = (cc0 & 7) << 4;
    const int cb1 = (cc1 << 9) + ((lane >> 4) * 16), xm1 = (cc1 & 7) << 4;
    const int ar    = rg * 16 + lrow;
    const int abase = AOFF + ar * 256;
    const int as    = ar & 7;

    int rout[4];
    #pragma unroll
    for (int reg = 0; reg < 4; ++reg) {
        int ri = rowBase + rg * 16 + (lane >> 4) * 4 + reg;
        if (ri > n - 1) ri = n - 1;
        rout[reg] = perm[ri];
    }

    #pragma unroll
    for (int h = 0; h < HALVES; ++h) {
        if (h > 0) {
            __syncthreads();
            const char* wsrc = (const char*)(Wsz + (size_t)h * 64 * 256);
            #pragma unroll
            for (int i = 0; i < 4; ++i) {
                const int off = (i * 512 + tid) * 16;
                __builtin_amdgcn_global_load_lds(
                    (const __attribute__((address_space(1))) unsigned int*)(wsrc + off),
                    (__attribute__((address_space(3))) unsigned int*)(smem + off),
                    16, 0, 0);
            }
            __syncthreads();
        }

        f32x4 acc0 = (f32x4){0.f, 0.f, 0.f, 0.f};
        f32x4 acc1 = (f32x4){0.f, 0.f, 0.f, 0.f};

        #pragma unroll
        for (int ks = 0; ks < 8; ++ks) {
            bf16x8 a;
            if (ks < 4)
                a = *(const bf16x8*)(smem + abase + (((ks * 4 + (lane >> 4)) ^ as) << 4));
            else
                a = xr[ks - 4];
            bf16x8 b0 = *(const bf16x8*)(smem + ((cb0 + (ks << 6)) ^ xm0));
            bf16x8 b1 = *(const bf16x8*)(smem + ((cb1 + (ks << 6)) ^ xm1));
            acc0 = __builtin_amdgcn_mfma_f32_16x16x32_bf16(a, b0, acc0, 0, 0, 0);
            acc1 = __builtin_amdgcn_mfma_f32_16x16x32_bf16(a, b1, acc1, 0, 0, 0);
        }

        #pragma unroll
        for (int nf = 0; nf < 2; ++nf) {
            const f32x4 av = nf ? acc1 : acc0;
            const int c = h * 64 + cg * 32 + nf * 16 + lrow;
            const float bv = bias[c];
            #pragma unroll
            for (int reg = 0; reg < 4; ++reg) {
                const int r = rout[reg];
                float hv = av[reg] + bv;
                if (RELU) hv = fmaxf(hv, 0.f);
                if (FINAL) {
                    outF[(size_t)r * NOUT + c] = hv;
                } else {
                    outC[(size_t)r * RS + c] = f2bf(hv);
                    outQ[(size_t)r * NFEAT + c] =
                        (unsigned char)(__builtin_amdgcn_cvt_pk_fp8_f32(hv, hv, 0, false) & 0xFF);
                }
            }
        }
    }
}

extern "C" void kernel_launch(void* const* d_in, const int* in_sizes, int n_in,
                              void* d_out, int out_size, void* d_ws, size_t ws_size,
                              hipStream_t stream) {
    const float* x   = (const float*)d_in[0];
    const int*   ei  = (const int*)d_in[1];
    const float* Wl0 = (const float*)d_in[2];
    const float* Wr0 = (const float*)d_in[3];
    const float* b0  = (const float*)d_in[4];
    const float* Wl1 = (const float*)d_in[5];
    const float* Wr1 = (const float*)d_in[6];
    const float* b1  = (const float*)d_in[7];
    const float* Wl2 = (const float*)d_in[8];
    const float* Wr2 = (const float*)d_in[9];
    const float* b2  = (const float*)d_in[10];

    const int nN = in_sizes[0] / NFEAT;       // 50000
    const int nE = in_sizes[1] / 2;           // 800000
    const int* src = ei;
    const int* dst = ei + nE;

    char* ws = (char*)d_ws;
    size_t off = 0;
    auto take = [&](size_t bytes) { char* p = ws + off; off += (bytes + 255) & ~(size_t)255; return p; };
    int*   cnt      = (int*)  take((size_t)nN * 4);
    int*   row_ptr  = (int*)  take((size_t)(nN + 1) * 4);
    int*   col_idx  = (int*)  take((size_t)nE * 4);
    float* inv_deg  = (float*)take((size_t)nN * 4);
    int*   blockSum = (int*)  take(256 * 4);
    int*   degHist  = (int*)  take(256 * 4);
    int*   perm     = (int*)  take((size_t)nN * 4);
    const size_t plane  = (size_t)nN * RS * 2;            // 12.8 MB bf16
    const size_t qplane = (size_t)nN * NFEAT;             // 6.4 MB fp8
    unsigned short* xc0  = (unsigned short*)take(plane);
    unsigned short* xc1  = (unsigned short*)take(plane);
    unsigned char*  xq0  = (unsigned char*) take(qplane);
    unsigned char*  xq1  = (unsigned char*) take(qplane);
    unsigned short* Wsz0 = (unsigned short*)take(128 * 256 * 2);
    unsigned short* Wsz1 = (unsigned short*)take(128 * 256 * 2);
    unsigned short* Wsz2 = (unsigned short*)take(64 * 256 * 2);
    (void)ws_size; (void)n_in; (void)out_size;

    const int scanBlocks = (nN + 255) / 256;
    const int sliceN = (nN + 7) / 8;

    // prep: xconv + wconv x3 + zero(cnt, degHist) in one launch
    const int prepTotal = nN * 32 + 81920 + nN + 256;
    prep_kernel<<<(prepTotal + 255) / 256, 256, 0, stream>>>(
        x, xc0, xq0, Wl0, Wr0, Wl1, Wr1, Wl2, Wr2, Wsz0, Wsz1, Wsz2, cnt, degHist, nN);

    // CSR build (XCD-sliced hist/fill) + degree-sort permutation (heavy-first)
    hist_kernel<<<2048, 256, 0, stream>>>(dst, cnt, nE, sliceN);
    blocksum_kernel<<<scanBlocks, 256, 0, stream>>>(cnt, blockSum, nN);
    scan_write_kernel<<<scanBlocks, 256, 0, stream>>>(cnt, blockSum, row_ptr, inv_deg, degHist, nN);
    fill_kernel<<<2048, 256, 0, stream>>>(src, dst, cnt, col_idx, nE, sliceN);
    bin_scan_kernel<<<1, 256, 0, stream>>>(degHist);
    scatter_kernel<<<scanBlocks, 256, 0, stream>>>(row_ptr, degHist, perm, nN);

    const int layerGrid = (nN + 63) / 64;     // 782

    // layer 0: x -> h0
    layer_kernel<128, true, false><<<layerGrid, 512, 0, stream>>>(
        xq0, xc0, row_ptr, col_idx, inv_deg, perm, Wsz0, b0, nullptr, xc1, xq1, nN);
    // layer 1: h0 -> h1
    layer_kernel<128, true, false><<<layerGrid, 512, 0, stream>>>(
        xq1, xc1, row_ptr, col_idx, inv_deg, perm, Wsz1, b1, nullptr, xc0, xq0, nN);
    // layer 2: h1 -> out (fp32)
    layer_kernel<64, false, true><<<layerGrid, 512, 0, stream>>>(
        xq0, xc0, row_ptr, col_idx, inv_deg, perm, Wsz2, b2, (float*)d_out, nullptr, nullptr, nN);
}